// Round 1
// baseline (6197.372 us; speedup 1.0000x reference)
//
#include <hip/hip_runtime.h>
#include <hip/hip_bf16.h>
#include <cstdint>

// Problem dims
#define DD 1024       // channels
#define LIN 1024      // input length
#define LP 511        // output length (1024-4)/2+1
#define LPAD 512      // padded stride for intermediates
#define NBATCH 32
#define KCB 2048      // codebook size
#define BN_EPS 1e-5f

// Output layout (floats): q_st [32,1024,511], ids [32,511], commitment, codebook_loss
#define OUT_IDS 16744448u      // 32*1024*511
#define OUT_LOSS 16760800u     // + 32*511

// Workspace layout (float offsets)
#define WS_H1 0                         // 32*1024*512 = 16777216
#define WS_T2 16777216                  // 16777216
#define WS_AUX 33554432
#define WS_A1 (WS_AUX + 0)
#define WS_B1 (WS_AUX + 1024)
#define WS_A2 (WS_AUX + 2048)
#define WS_B2 (WS_AUX + 3072)
#define WS_E2 (WS_AUX + 4096)           // 2048
#define WS_SLOTS (WS_AUX + 6144)        // u64 x 16352 = 32704 floats
#define WS_LOSS (WS_AUX + 6144 + 32704)

// ---------------------------------------------------------------------------
// block reduce (256 threads = 4 waves)
__device__ inline float blockReduce256(float v, float* sb) {
#pragma unroll
  for (int off = 32; off > 0; off >>= 1) v += __shfl_down(v, off);
  __syncthreads();
  if ((threadIdx.x & 63) == 0) sb[threadIdx.x >> 6] = v;
  __syncthreads();
  return sb[0] + sb[1] + sb[2] + sb[3];
}

// ---------------------------------------------------------------------------
// conv1: h[n,o,l'] = sum_{i,t} x[n,i,2l'+t] * w[o,i,t] + b[o]
// 128x128 tile per block, 8x8 micro-tile, K-chunk = 8 channels (32 K-steps)
__global__ __launch_bounds__(256) void conv1_kernel(
    const float* __restrict__ x, const float* __restrict__ w,
    const float* __restrict__ bias, float* __restrict__ h) {
  __shared__ float wT[32 * 132];   // [it=i_local*4+t][o_local], pad 132
  __shared__ float xs[8 * 264];    // [i_local][x-col 0..257], pad 264
  const int lb = blockIdx.x * 128;
  const int ob = blockIdx.y * 128;
  const int n = blockIdx.z;
  const int tid = threadIdx.x;
  const int tx = tid & 15;   // l' dim: l = lb + tx + 16*jj
  const int ty = tid >> 4;   // o  dim: o = ob + ty*8 + j

  float acc[8][8];
#pragma unroll
  for (int j = 0; j < 8; ++j)
#pragma unroll
    for (int jj = 0; jj < 8; ++jj) acc[j][jj] = 0.f;

  const float* xn = x + (size_t)n * DD * LIN;

  for (int i0 = 0; i0 < DD; i0 += 8) {
    // stage W: 128 o x 32 it  (coalesced: 32 contiguous floats per o row)
#pragma unroll
    for (int r = 0; r < 16; ++r) {
      int idx = tid + 256 * r;
      int ol = idx >> 5, it = idx & 31;
      wT[it * 132 + ol] = w[(size_t)(ob + ol) * 4096 + i0 * 4 + it];
    }
    // stage X: 8 rows x 258 cols (x-cols 2*lb .. 2*lb+257)
#pragma unroll
    for (int r = 0; r < 9; ++r) {
      int idx = tid + 256 * r;
      if (idx < 8 * 264) {
        int il = idx / 264, col = idx - il * 264;
        int gc = 2 * lb + col;
        float v = 0.f;
        if (col < 258 && gc < LIN) v = xn[(size_t)(i0 + il) * LIN + gc];
        xs[il * 264 + col] = v;
      }
    }
    __syncthreads();
#pragma unroll
    for (int il = 0; il < 8; ++il) {
#pragma unroll
      for (int t = 0; t < 4; ++t) {
        const int it = il * 4 + t;
        const float4 af0 = *(const float4*)&wT[it * 132 + ty * 8];
        const float4 af1 = *(const float4*)&wT[it * 132 + ty * 8 + 4];
        const float av[8] = {af0.x, af0.y, af0.z, af0.w, af1.x, af1.y, af1.z, af1.w};
        float bv[8];
#pragma unroll
        for (int jj = 0; jj < 8; ++jj) bv[jj] = xs[il * 264 + 2 * tx + 32 * jj + t];
#pragma unroll
        for (int j = 0; j < 8; ++j)
#pragma unroll
          for (int jj = 0; jj < 8; ++jj) acc[j][jj] = fmaf(av[j], bv[jj], acc[j][jj]);
      }
    }
    __syncthreads();
  }

#pragma unroll
  for (int j = 0; j < 8; ++j) {
    const int o = ob + ty * 8 + j;
    const float bo = bias[o];
    float* hp = h + ((size_t)n * DD + o) * LPAD;
#pragma unroll
    for (int jj = 0; jj < 8; ++jj) {
      const int l = lb + tx + 16 * jj;
      if (l < LP) hp[l] = acc[j][jj] + bo;
    }
  }
}

// ---------------------------------------------------------------------------
// BN training-mode stats per channel over (N, L'); emits a = g*rsqrt(var+eps),
// b = beta - mean*a  so downstream applies z = a*x + b.
__global__ __launch_bounds__(256) void bn_stats_kernel(
    const float* __restrict__ src, const float* __restrict__ gamma,
    const float* __restrict__ beta, float* __restrict__ a_out,
    float* __restrict__ b_out) {
  __shared__ float sb[4];
  const int c = blockIdx.x;
  const float* p = src + (size_t)c * LPAD;
  float s1 = 0.f, s2 = 0.f;
  for (int idx = threadIdx.x; idx < NBATCH * LP; idx += 256) {
    int nn = idx / LP;
    int l = idx - nn * LP;
    float v = p[(size_t)nn * DD * LPAD + l];
    s1 += v;
    s2 = fmaf(v, v, s2);
  }
  s1 = blockReduce256(s1, sb);
  s2 = blockReduce256(s2, sb);
  if (threadIdx.x == 0) {
    const float inv = 1.f / (float)(NBATCH * LP);
    float m = s1 * inv;
    float var = fmaf(-m, m, s2 * inv);
    float a = gamma[c] * rsqrtf(var + BN_EPS);
    a_out[c] = a;
    b_out[c] = fmaf(-m, a, beta[c]);
  }
}

// ---------------------------------------------------------------------------
// conv2 fused: t2 = h + W2 @ relu(a1*h + b1) + b2c   (1x1 conv + residual)
__global__ __launch_bounds__(256) void conv2_kernel(
    const float* __restrict__ h1, const float* __restrict__ w2,
    const float* __restrict__ b2c, const float* __restrict__ a1,
    const float* __restrict__ b1, float* __restrict__ t2) {
  __shared__ float wT[8 * 132];  // [i_local][o_local]
  __shared__ float xs[8 * 128];  // [i_local][l_col]
  const int lb = blockIdx.x * 128;
  const int ob = blockIdx.y * 128;
  const int n = blockIdx.z;
  const int tid = threadIdx.x, tx = tid & 15, ty = tid >> 4;

  float acc[8][8];
#pragma unroll
  for (int j = 0; j < 8; ++j)
#pragma unroll
    for (int jj = 0; jj < 8; ++jj) acc[j][jj] = 0.f;

  const float* hn = h1 + (size_t)n * DD * LPAD;

  for (int i0 = 0; i0 < DD; i0 += 8) {
#pragma unroll
    for (int r = 0; r < 4; ++r) {
      int idx = tid + 256 * r;
      int il = idx & 7, ol = idx >> 3;
      wT[il * 132 + ol] = w2[(size_t)(ob + ol) * DD + i0 + il];
    }
#pragma unroll
    for (int r = 0; r < 4; ++r) {
      int idx = tid + 256 * r;
      int col = idx & 127, il = idx >> 7;
      float v = hn[(size_t)(i0 + il) * LPAD + lb + col];
      xs[il * 128 + col] = fmaxf(fmaf(a1[i0 + il], v, b1[i0 + il]), 0.f);
    }
    __syncthreads();
#pragma unroll
    for (int il = 0; il < 8; ++il) {
      const float4 af0 = *(const float4*)&wT[il * 132 + ty * 8];
      const float4 af1 = *(const float4*)&wT[il * 132 + ty * 8 + 4];
      const float av[8] = {af0.x, af0.y, af0.z, af0.w, af1.x, af1.y, af1.z, af1.w};
      float bv[8];
#pragma unroll
      for (int jj = 0; jj < 8; ++jj) bv[jj] = xs[il * 128 + tx + 16 * jj];
#pragma unroll
      for (int j = 0; j < 8; ++j)
#pragma unroll
        for (int jj = 0; jj < 8; ++jj) acc[j][jj] = fmaf(av[j], bv[jj], acc[j][jj]);
    }
    __syncthreads();
  }

#pragma unroll
  for (int j = 0; j < 8; ++j) {
    const int o = ob + ty * 8 + j;
    const float bo = b2c[o];
    const float* hp = hn + (size_t)o * LPAD;
    float* tp = t2 + ((size_t)n * DD + o) * LPAD;
#pragma unroll
    for (int jj = 0; jj < 8; ++jj) {
      const int l = lb + tx + 16 * jj;
      if (l < LP) tp[l] = hp[l] + acc[j][jj] + bo;
    }
  }
}

// ---------------------------------------------------------------------------
// codebook row norms ||e_k||^2
__global__ __launch_bounds__(256) void e2_kernel(const float* __restrict__ cb,
                                                 float* __restrict__ e2) {
  __shared__ float sb[4];
  const int k = blockIdx.x;
  float s = 0.f;
  for (int d = threadIdx.x; d < DD; d += 256) {
    float v = cb[(size_t)k * DD + d];
    s = fmaf(v, v, s);
  }
  s = blockReduce256(s, sb);
  if (threadIdx.x == 0) e2[k] = s;
}

// ---------------------------------------------------------------------------
// dist: S = cb @ z  (z = a2*t2 + b2 on the fly); argmin(e2 - 2S) per position
// via packed (dist_bits<<32 | k) atomicMin. 128 codes x 128 positions / block.
__global__ __launch_bounds__(256) void dist_kernel(
    const float* __restrict__ t2, const float* __restrict__ cb,
    const float* __restrict__ a2, const float* __restrict__ b2,
    const float* __restrict__ e2, unsigned long long* __restrict__ slots) {
  __shared__ float eT[8 * 132];  // [d_local][k_col]
  __shared__ float zs[8 * 128];  // [d_local][l_col]
  __shared__ unsigned long long best[128];
  const int lb = blockIdx.x * 128;
  const int kb = blockIdx.y * 128;
  const int n = blockIdx.z;
  const int tid = threadIdx.x, tx = tid & 15, ty = tid >> 4;

  float acc[8][8];
#pragma unroll
  for (int j = 0; j < 8; ++j)
#pragma unroll
    for (int jj = 0; jj < 8; ++jj) acc[j][jj] = 0.f;

  const float* tn = t2 + (size_t)n * DD * LPAD;

  for (int d0 = 0; d0 < DD; d0 += 8) {
#pragma unroll
    for (int r = 0; r < 4; ++r) {
      int idx = tid + 256 * r;
      int il = idx & 7, kc = idx >> 3;
      eT[il * 132 + kc] = cb[(size_t)(kb + kc) * DD + d0 + il];
    }
#pragma unroll
    for (int r = 0; r < 4; ++r) {
      int idx = tid + 256 * r;
      int col = idx & 127, il = idx >> 7;
      zs[il * 128 + col] =
          fmaf(a2[d0 + il], tn[(size_t)(d0 + il) * LPAD + lb + col], b2[d0 + il]);
    }
    __syncthreads();
#pragma unroll
    for (int il = 0; il < 8; ++il) {
      const float4 af0 = *(const float4*)&eT[il * 132 + ty * 8];
      const float4 af1 = *(const float4*)&eT[il * 132 + ty * 8 + 4];
      const float av[8] = {af0.x, af0.y, af0.z, af0.w, af1.x, af1.y, af1.z, af1.w};
      float bv[8];
#pragma unroll
      for (int jj = 0; jj < 8; ++jj) bv[jj] = zs[il * 128 + tx + 16 * jj];
#pragma unroll
      for (int j = 0; j < 8; ++j)
#pragma unroll
        for (int jj = 0; jj < 8; ++jj) acc[j][jj] = fmaf(av[j], bv[jj], acc[j][jj]);
    }
    __syncthreads();
  }

  if (tid < 128) best[tid] = ~0ULL;
  __syncthreads();
#pragma unroll
  for (int jj = 0; jj < 8; ++jj) {
    const int col = tx + 16 * jj;
    float dmin = 3.4e38f;
    int kmin = 0;
#pragma unroll
    for (int j = 0; j < 8; ++j) {
      const int k = kb + ty * 8 + j;
      float dist = fmaf(-2.f, acc[j][jj], e2[k]);
      if (dist < dmin) { dmin = dist; kmin = k; }
    }
    unsigned long long pk =
        ((unsigned long long)__float_as_uint(dmin) << 32) | (unsigned)kmin;
    atomicMin(&best[col], pk);
  }
  __syncthreads();
  if (tid < 128) {
    int l = lb + tid;
    if (l < LP) atomicMin(&slots[(size_t)n * LP + l], best[tid]);
  }
}

// ---------------------------------------------------------------------------
// gather: ids (as float), q_st = codebook[ids] in [n,d,l'] layout, loss sum
__global__ __launch_bounds__(256) void gather_kernel(
    const float* __restrict__ t2, const float* __restrict__ cb,
    const float* __restrict__ a2, const float* __restrict__ b2,
    const unsigned long long* __restrict__ slots, float* __restrict__ out,
    float* __restrict__ loss_acc) {
  __shared__ int ks[64];
  __shared__ float sb[4];
  const int l0 = blockIdx.x * 64;
  const int n = blockIdx.y;
  const int tid = threadIdx.x, tx = tid & 63, ty = tid >> 6;
  if (tid < 64) {
    int l = l0 + tid;
    int k = 0;
    if (l < LP) {
      k = (int)(unsigned)(slots[(size_t)n * LP + l] & 0xffffffffULL);
      out[OUT_IDS + (size_t)n * LP + l] = (float)k;
    }
    ks[tid] = k;
  }
  __syncthreads();
  const int l = l0 + tx;
  const bool valid = (l < LP);
  const int k = ks[tx];
  const float* cbk = cb + (size_t)k * DD;
  const float* tn = t2 + (size_t)n * DD * LPAD;
  float* qo = out + (size_t)n * DD * LP;
  float lsum = 0.f;
  for (int d0 = 0; d0 < DD; d0 += 4) {
    const int d = d0 + ty;
    float q = cbk[d];
    if (valid) {
      float z = fmaf(a2[d], tn[(size_t)d * LPAD + l], b2[d]);
      qo[(size_t)d * LP + l] = q;
      float e = z - q;
      lsum = fmaf(e, e, lsum);
    }
  }
  lsum = blockReduce256(lsum, sb);
  if (tid == 0) atomicAdd(loss_acc, lsum);
}

__global__ void finalize_kernel(const float* __restrict__ loss_acc,
                                float* __restrict__ out) {
  if (threadIdx.x == 0) {
    float m = loss_acc[0] * (1.f / 16744448.f);  // mean over 32*511*1024
    out[OUT_LOSS] = m;       // commitment
    out[OUT_LOSS + 1] = m;   // codebook_loss (identical forward value)
  }
}

// ---------------------------------------------------------------------------
extern "C" void kernel_launch(void* const* d_in, const int* in_sizes, int n_in,
                              void* d_out, int out_size, void* d_ws,
                              size_t ws_size, hipStream_t stream) {
  const float* x = (const float*)d_in[0];
  const float* w1 = (const float*)d_in[1];
  const float* b1c = (const float*)d_in[2];
  const float* g1 = (const float*)d_in[3];
  const float* be1 = (const float*)d_in[4];
  const float* w2 = (const float*)d_in[5];
  const float* b2c = (const float*)d_in[6];
  const float* g2 = (const float*)d_in[7];
  const float* be2 = (const float*)d_in[8];
  const float* cb = (const float*)d_in[9];
  float* out = (float*)d_out;
  float* ws = (float*)d_ws;

  float* h1 = ws + WS_H1;
  float* t2 = ws + WS_T2;
  float* a1 = ws + WS_A1;
  float* bb1 = ws + WS_B1;
  float* a2 = ws + WS_A2;
  float* bb2 = ws + WS_B2;
  float* e2 = ws + WS_E2;
  unsigned long long* slots = (unsigned long long*)(ws + WS_SLOTS);
  float* loss = ws + WS_LOSS;

  hipMemsetAsync(slots, 0xFF, (size_t)NBATCH * LP * sizeof(unsigned long long),
                 stream);
  hipMemsetAsync(loss, 0, sizeof(float), stream);

  conv1_kernel<<<dim3(4, 8, NBATCH), 256, 0, stream>>>(x, w1, b1c, h1);
  bn_stats_kernel<<<DD, 256, 0, stream>>>(h1, g1, be1, a1, bb1);
  conv2_kernel<<<dim3(4, 8, NBATCH), 256, 0, stream>>>(h1, w2, b2c, a1, bb1, t2);
  bn_stats_kernel<<<DD, 256, 0, stream>>>(t2, g2, be2, a2, bb2);
  e2_kernel<<<KCB, 256, 0, stream>>>(cb, e2);
  dist_kernel<<<dim3(4, 16, NBATCH), 256, 0, stream>>>(t2, cb, a2, bb2, e2, slots);
  gather_kernel<<<dim3(8, NBATCH), 256, 0, stream>>>(t2, cb, a2, bb2, slots, out, loss);
  finalize_kernel<<<1, 64, 0, stream>>>(loss, out);
}

// Round 2
// 2396.524 us; speedup vs baseline: 2.5860x; 2.5860x over previous
//
#include <hip/hip_runtime.h>
#include <hip/hip_bf16.h>
#include <cstdint>

// Problem dims
#define DD 1024       // channels
#define LIN 1024      // input length
#define LP 511        // output length (1024-4)/2+1
#define LPAD 512      // padded stride for intermediates
#define NBATCH 32
#define KCB 2048      // codebook size
#define BN_EPS 1e-5f

// Output layout (floats): q_st [32,1024,511], ids [32,511], commitment, codebook_loss
#define OUT_IDS 16744448u      // 32*1024*511
#define OUT_LOSS 16760800u     // + 32*511

// Workspace layout (float offsets)
// h1 fp32 [32][1024][512]
#define WS_H1 0
// union region: phase1 = x bf16 planes + w planes (conv1 only); phase2 = t2
#define WS_UNI 16777216
#define WS_XH  (WS_UNI)                    // [2][32][512][1024] ushort = 16,777,216 floats (+512 pad)
#define WS_XL  (WS_UNI + 16777728)         // same size (+512 pad)
#define WS_WTH (WS_UNI + 33555456)         // [4][1024][1024] ushort = 2,097,152 floats
#define WS_WTL (WS_UNI + 35652608)         // same
#define WS_T2  (WS_UNI)                    // phase2: fp32 [32][1024][512]
#define WS_AUX (WS_UNI + 37749760)
#define WS_A1 (WS_AUX + 0)
#define WS_B1 (WS_AUX + 1024)
#define WS_A2 (WS_AUX + 2048)
#define WS_B2 (WS_AUX + 3072)
#define WS_E2 (WS_AUX + 4096)
#define WS_SLOTS (WS_AUX + 6144)           // u64 x 16352
#define WS_LOSS (WS_AUX + 6144 + 32704)

typedef __attribute__((ext_vector_type(8))) short bf16x8;
typedef __attribute__((ext_vector_type(4))) float f32x4;

__device__ __forceinline__ void async_cp16(const void* gsrc, void* ldst) {
  __builtin_amdgcn_global_load_lds(
      (const __attribute__((address_space(1))) unsigned int*)gsrc,
      (__attribute__((address_space(3))) unsigned int*)ldst, 16, 0, 0);
}

__device__ __forceinline__ void bf16split(float v, unsigned short& hi, unsigned short& lo) {
  __hip_bfloat16 h = __float2bfloat16(v);
  float hf = __bfloat162float(h);
  __hip_bfloat16 l = __float2bfloat16(v - hf);
  hi = *(unsigned short*)&h;
  lo = *(unsigned short*)&l;
}

// ---------------------------------------------------------------------------
__device__ inline float blockReduce256(float v, float* sb) {
#pragma unroll
  for (int off = 32; off > 0; off >>= 1) v += __shfl_down(v, off);
  __syncthreads();
  if ((threadIdx.x & 63) == 0) sb[threadIdx.x >> 6] = v;
  __syncthreads();
  return sb[0] + sb[1] + sb[2] + sb[3];
}

// ---------------------------------------------------------------------------
// split w1 [o][i][t] fp32 -> wth/wtl [t][o][i] bf16 hi/lo
__global__ __launch_bounds__(256) void split_w1_kernel(
    const float* __restrict__ w, unsigned short* __restrict__ wth,
    unsigned short* __restrict__ wtl) {
  int idx = blockIdx.x * 256 + threadIdx.x;   // 0 .. 1024*1024-1
  int o = idx >> 10, i = idx & 1023;
  float4 v = *(const float4*)&w[(size_t)idx * 4];
  float vv[4] = {v.x, v.y, v.z, v.w};
#pragma unroll
  for (int t = 0; t < 4; ++t) {
    unsigned short hi, lo;
    bf16split(vv[t], hi, lo);
    size_t off = (((size_t)(t << 10) + o) << 10) + i;
    wth[off] = hi;
    wtl[off] = lo;
  }
}

// ---------------------------------------------------------------------------
// split/transpose x [n][i][l] fp32 -> xh/xl [P][n][l>>1][i] bf16 (P = l&1)
__global__ __launch_bounds__(256) void split_x_kernel(
    const float* __restrict__ x, unsigned short* __restrict__ xh,
    unsigned short* __restrict__ xl) {
  __shared__ float lsT[128 * 65];  // [col][row] transposed, pad 65
  const int l0 = blockIdx.x * 128;
  const int i0 = blockIdx.y * 64;
  const int nB = blockIdx.z;
  const int tid = threadIdx.x;
  // read 64 rows x 128 cols, store transposed
#pragma unroll
  for (int p = 0; p < 8; ++p) {
    int flat = p * 256 + tid;
    int row = flat >> 5, col4 = (flat & 31) * 4;
    float4 v = *(const float4*)&x[((size_t)nB * DD + i0 + row) * LIN + l0 + col4];
    lsT[(col4 + 0) * 65 + row] = v.x;
    lsT[(col4 + 1) * 65 + row] = v.y;
    lsT[(col4 + 2) * 65 + row] = v.z;
    lsT[(col4 + 3) * 65 + row] = v.w;
  }
  __syncthreads();
  const int lo2 = (l0 >> 1);
#pragma unroll
  for (int p = 0; p < 16; ++p) {
    int cp = p * 4 + (tid >> 6);   // 0..63 output col
    int il = tid & 63;
    float vE = lsT[(2 * cp) * 65 + il];
    float vO = lsT[(2 * cp + 1) * 65 + il];
    unsigned short hE, lE, hO, lO;
    bf16split(vE, hE, lE);
    bf16split(vO, hO, lO);
    size_t dE = (((size_t)(0 * 32 + nB) * 512) + lo2 + cp) * 1024 + i0 + il;
    size_t dO = (((size_t)(1 * 32 + nB) * 512) + lo2 + cp) * 1024 + i0 + il;
    xh[dE] = hE; xl[dE] = lE;
    xh[dO] = hO; xl[dO] = lO;
  }
}

// ---------------------------------------------------------------------------
// conv1 as MFMA GEMM, bf16 3-term split.
// h[n,o,l'] = sum_{t,i} w[o,i,t] * x[n,i,2l'+t] + b[o]
// A = wt[t][o][i] (M=o, K=(t,i)); B = xplane[t&1][n][l'+ (t>>1)][i] (N=l')
// 128x128 tile, 4 waves 2x2 each 64x64, BK=32 (one t, 32 channels)
__global__ __launch_bounds__(256) void conv1_mfma_kernel(
    const unsigned short* __restrict__ wth, const unsigned short* __restrict__ wtl,
    const unsigned short* __restrict__ xh, const unsigned short* __restrict__ xl,
    const float* __restrict__ bias, float* __restrict__ h1) {
  __shared__ unsigned short sm[16384];  // Ah[128][32] | Al | Bh | Bl  (8KB each)
  const int tid = threadIdx.x;
  const int wid = tid >> 6, lane = tid & 63;
  const int lb = blockIdx.x * 128, ob = blockIdx.y * 128, nB = blockIdx.z;

  f32x4 acc[4][4];
#pragma unroll
  for (int a = 0; a < 4; ++a)
#pragma unroll
    for (int b = 0; b < 4; ++b) acc[a][b] = (f32x4){0.f, 0.f, 0.f, 0.f};

  const int wm = wid & 1, wn = wid >> 1;
  const int mrow = (wm << 6) + (lane & 15);
  const int nrow = (wn << 6) + (lane & 15);
  const int ko = (lane >> 4) << 3;
  const unsigned short* As = sm;
  const unsigned short* Als = sm + 4096;
  const unsigned short* Bs = sm + 8192;
  const unsigned short* Bls = sm + 12288;

  for (int kc = 0; kc < 128; ++kc) {
    const int t = kc >> 5;
    const int i0 = (kc & 31) << 5;
    const unsigned short* src;
    if (wid == 0)
      src = wth + (((size_t)(t << 10) + ob) << 10) + i0;
    else if (wid == 1)
      src = wtl + (((size_t)(t << 10) + ob) << 10) + i0;
    else {
      const unsigned short* xp = (wid == 2) ? xh : xl;
      src = xp + ((((size_t)((t & 1) * 32 + nB) * 512) + lb + (t >> 1)) << 10) + i0;
    }
    const unsigned short* lanesrc = src + (size_t)(lane >> 2) * 1024 + (lane & 3) * 8;
    char* ldsbase = (char*)sm + wid * 8192;
#pragma unroll
    for (int q = 0; q < 8; ++q)
      async_cp16(lanesrc + q * 16 * 1024, ldsbase + q * 1024);
    __syncthreads();

    bf16x8 fbh[4], fbl[4];
#pragma unroll
    for (int nt = 0; nt < 4; ++nt) {
      int r = nrow + nt * 16;
      fbh[nt] = *(const bf16x8*)(Bs + r * 32 + ko);
      fbl[nt] = *(const bf16x8*)(Bls + r * 32 + ko);
    }
#pragma unroll
    for (int mt = 0; mt < 4; ++mt) {
      int r = mrow + mt * 16;
      bf16x8 fah = *(const bf16x8*)(As + r * 32 + ko);
      bf16x8 fal = *(const bf16x8*)(Als + r * 32 + ko);
#pragma unroll
      for (int nt = 0; nt < 4; ++nt) {
        acc[mt][nt] = __builtin_amdgcn_mfma_f32_16x16x32_bf16(fah, fbh[nt], acc[mt][nt], 0, 0, 0);
        acc[mt][nt] = __builtin_amdgcn_mfma_f32_16x16x32_bf16(fah, fbl[nt], acc[mt][nt], 0, 0, 0);
        acc[mt][nt] = __builtin_amdgcn_mfma_f32_16x16x32_bf16(fal, fbh[nt], acc[mt][nt], 0, 0, 0);
      }
    }
    __syncthreads();
  }

  // epilogue: C row=(lane>>4)*4+rg (m=o), col=lane&15 (n=l')
#pragma unroll
  for (int mt = 0; mt < 4; ++mt) {
    const int o_base = ob + (wm << 6) + mt * 16 + ((lane >> 4) << 2);
#pragma unroll
    for (int nt = 0; nt < 4; ++nt) {
      const int l = lb + (wn << 6) + nt * 16 + (lane & 15);
      if (l < LP) {
#pragma unroll
        for (int rg = 0; rg < 4; ++rg)
          h1[((size_t)(nB << 10) + o_base + rg) * LPAD + l] =
              acc[mt][nt][rg] + bias[o_base + rg];
      }
    }
  }
}

// ---------------------------------------------------------------------------
// BN training-mode stats per channel over (N, L'); emits a,b for z = a*x+b
__global__ __launch_bounds__(256) void bn_stats_kernel(
    const float* __restrict__ src, const float* __restrict__ gamma,
    const float* __restrict__ beta, float* __restrict__ a_out,
    float* __restrict__ b_out) {
  __shared__ float sb[4];
  const int c = blockIdx.x;
  const float* p = src + (size_t)c * LPAD;
  float s1 = 0.f, s2 = 0.f;
  for (int idx = threadIdx.x; idx < NBATCH * LP; idx += 256) {
    int nn = idx / LP;
    int l = idx - nn * LP;
    float v = p[(size_t)nn * DD * LPAD + l];
    s1 += v;
    s2 = fmaf(v, v, s2);
  }
  s1 = blockReduce256(s1, sb);
  s2 = blockReduce256(s2, sb);
  if (threadIdx.x == 0) {
    const float inv = 1.f / (float)(NBATCH * LP);
    float m = s1 * inv;
    float var = fmaf(-m, m, s2 * inv);
    float a = gamma[c] * rsqrtf(var + BN_EPS);
    a_out[c] = a;
    b_out[c] = fmaf(-m, a, beta[c]);
  }
}

// ---------------------------------------------------------------------------
// conv2 fused: t2 = h + W2 @ relu(a1*h + b1) + b2c
__global__ __launch_bounds__(256) void conv2_kernel(
    const float* __restrict__ h1, const float* __restrict__ w2,
    const float* __restrict__ b2c, const float* __restrict__ a1,
    const float* __restrict__ b1, float* __restrict__ t2) {
  __shared__ float wT[8 * 132];
  __shared__ float xs[8 * 128];
  const int lb = blockIdx.x * 128;
  const int ob = blockIdx.y * 128;
  const int n = blockIdx.z;
  const int tid = threadIdx.x, tx = tid & 15, ty = tid >> 4;

  float acc[8][8];
#pragma unroll
  for (int j = 0; j < 8; ++j)
#pragma unroll
    for (int jj = 0; jj < 8; ++jj) acc[j][jj] = 0.f;

  const float* hn = h1 + (size_t)n * DD * LPAD;

  for (int i0 = 0; i0 < DD; i0 += 8) {
#pragma unroll
    for (int r = 0; r < 4; ++r) {
      int idx = tid + 256 * r;
      int il = idx & 7, ol = idx >> 3;
      wT[il * 132 + ol] = w2[(size_t)(ob + ol) * DD + i0 + il];
    }
#pragma unroll
    for (int r = 0; r < 4; ++r) {
      int idx = tid + 256 * r;
      int col = idx & 127, il = idx >> 7;
      float v = hn[(size_t)(i0 + il) * LPAD + lb + col];
      xs[il * 128 + col] = fmaxf(fmaf(a1[i0 + il], v, b1[i0 + il]), 0.f);
    }
    __syncthreads();
#pragma unroll
    for (int il = 0; il < 8; ++il) {
      const float4 af0 = *(const float4*)&wT[il * 132 + ty * 8];
      const float4 af1 = *(const float4*)&wT[il * 132 + ty * 8 + 4];
      const float av[8] = {af0.x, af0.y, af0.z, af0.w, af1.x, af1.y, af1.z, af1.w};
      float bv[8];
#pragma unroll
      for (int jj = 0; jj < 8; ++jj) bv[jj] = xs[il * 128 + tx + 16 * jj];
#pragma unroll
      for (int j = 0; j < 8; ++j)
#pragma unroll
        for (int jj = 0; jj < 8; ++jj) acc[j][jj] = fmaf(av[j], bv[jj], acc[j][jj]);
    }
    __syncthreads();
  }

#pragma unroll
  for (int j = 0; j < 8; ++j) {
    const int o = ob + ty * 8 + j;
    const float bo = b2c[o];
    const float* hp = hn + (size_t)o * LPAD;
    float* tp = t2 + ((size_t)n * DD + o) * LPAD;
#pragma unroll
    for (int jj = 0; jj < 8; ++jj) {
      const int l = lb + tx + 16 * jj;
      if (l < LP) tp[l] = hp[l] + acc[j][jj] + bo;
    }
  }
}

// ---------------------------------------------------------------------------
__global__ __launch_bounds__(256) void e2_kernel(const float* __restrict__ cb,
                                                 float* __restrict__ e2) {
  __shared__ float sb[4];
  const int k = blockIdx.x;
  float s = 0.f;
  for (int d = threadIdx.x; d < DD; d += 256) {
    float v = cb[(size_t)k * DD + d];
    s = fmaf(v, v, s);
  }
  s = blockReduce256(s, sb);
  if (threadIdx.x == 0) e2[k] = s;
}

// ---------------------------------------------------------------------------
// dist: S = cb @ z (z = a2*t2+b2); argmin(e2 - 2S) via packed u64 atomicMin
__global__ __launch_bounds__(256) void dist_kernel(
    const float* __restrict__ t2, const float* __restrict__ cb,
    const float* __restrict__ a2, const float* __restrict__ b2,
    const float* __restrict__ e2, unsigned long long* __restrict__ slots) {
  __shared__ float eT[8 * 132];
  __shared__ float zs[8 * 128];
  __shared__ unsigned long long best[128];
  const int lb = blockIdx.x * 128;
  const int kb = blockIdx.y * 128;
  const int n = blockIdx.z;
  const int tid = threadIdx.x, tx = tid & 15, ty = tid >> 4;

  float acc[8][8];
#pragma unroll
  for (int j = 0; j < 8; ++j)
#pragma unroll
    for (int jj = 0; jj < 8; ++jj) acc[j][jj] = 0.f;

  const float* tn = t2 + (size_t)n * DD * LPAD;

  for (int d0 = 0; d0 < DD; d0 += 8) {
#pragma unroll
    for (int r = 0; r < 4; ++r) {
      int idx = tid + 256 * r;
      int il = idx & 7, kc = idx >> 3;
      eT[il * 132 + kc] = cb[(size_t)(kb + kc) * DD + d0 + il];
    }
#pragma unroll
    for (int r = 0; r < 4; ++r) {
      int idx = tid + 256 * r;
      int col = idx & 127, il = idx >> 7;
      zs[il * 128 + col] =
          fmaf(a2[d0 + il], tn[(size_t)(d0 + il) * LPAD + lb + col], b2[d0 + il]);
    }
    __syncthreads();
#pragma unroll
    for (int il = 0; il < 8; ++il) {
      const float4 af0 = *(const float4*)&eT[il * 132 + ty * 8];
      const float4 af1 = *(const float4*)&eT[il * 132 + ty * 8 + 4];
      const float av[8] = {af0.x, af0.y, af0.z, af0.w, af1.x, af1.y, af1.z, af1.w};
      float bv[8];
#pragma unroll
      for (int jj = 0; jj < 8; ++jj) bv[jj] = zs[il * 128 + tx + 16 * jj];
#pragma unroll
      for (int j = 0; j < 8; ++j)
#pragma unroll
        for (int jj = 0; jj < 8; ++jj) acc[j][jj] = fmaf(av[j], bv[jj], acc[j][jj]);
    }
    __syncthreads();
  }

  if (tid < 128) best[tid] = ~0ULL;
  __syncthreads();
#pragma unroll
  for (int jj = 0; jj < 8; ++jj) {
    const int col = tx + 16 * jj;
    float dmin = 3.4e38f;
    int kmin = 0;
#pragma unroll
    for (int j = 0; j < 8; ++j) {
      const int k = kb + ty * 8 + j;
      float dist = fmaf(-2.f, acc[j][jj], e2[k]);
      if (dist < dmin) { dmin = dist; kmin = k; }
    }
    unsigned long long pk =
        ((unsigned long long)__float_as_uint(dmin) << 32) | (unsigned)kmin;
    atomicMin(&best[col], pk);
  }
  __syncthreads();
  if (tid < 128) {
    int l = lb + tid;
    if (l < LP) atomicMin(&slots[(size_t)n * LP + l], best[tid]);
  }
}

// ---------------------------------------------------------------------------
__global__ __launch_bounds__(256) void gather_kernel(
    const float* __restrict__ t2, const float* __restrict__ cb,
    const float* __restrict__ a2, const float* __restrict__ b2,
    const unsigned long long* __restrict__ slots, float* __restrict__ out,
    float* __restrict__ loss_acc) {
  __shared__ int ks[64];
  __shared__ float sb[4];
  const int l0 = blockIdx.x * 64;
  const int n = blockIdx.y;
  const int tid = threadIdx.x, tx = tid & 63, ty = tid >> 6;
  if (tid < 64) {
    int l = l0 + tid;
    int k = 0;
    if (l < LP) {
      k = (int)(unsigned)(slots[(size_t)n * LP + l] & 0xffffffffULL);
      out[OUT_IDS + (size_t)n * LP + l] = (float)k;
    }
    ks[tid] = k;
  }
  __syncthreads();
  const int l = l0 + tx;
  const bool valid = (l < LP);
  const int k = ks[tx];
  const float* cbk = cb + (size_t)k * DD;
  const float* tn = t2 + (size_t)n * DD * LPAD;
  float* qo = out + (size_t)n * DD * LP;
  float lsum = 0.f;
  for (int d0 = 0; d0 < DD; d0 += 4) {
    const int d = d0 + ty;
    float q = cbk[d];
    if (valid) {
      float z = fmaf(a2[d], tn[(size_t)d * LPAD + l], b2[d]);
      qo[(size_t)d * LP + l] = q;
      float e = z - q;
      lsum = fmaf(e, e, lsum);
    }
  }
  lsum = blockReduce256(lsum, sb);
  if (tid == 0) atomicAdd(loss_acc, lsum);
}

__global__ void finalize_kernel(const float* __restrict__ loss_acc,
                                float* __restrict__ out) {
  if (threadIdx.x == 0) {
    float m = loss_acc[0] * (1.f / 16744448.f);
    out[OUT_LOSS] = m;
    out[OUT_LOSS + 1] = m;
  }
}

// ---------------------------------------------------------------------------
extern "C" void kernel_launch(void* const* d_in, const int* in_sizes, int n_in,
                              void* d_out, int out_size, void* d_ws,
                              size_t ws_size, hipStream_t stream) {
  const float* x = (const float*)d_in[0];
  const float* w1 = (const float*)d_in[1];
  const float* b1c = (const float*)d_in[2];
  const float* g1 = (const float*)d_in[3];
  const float* be1 = (const float*)d_in[4];
  const float* w2 = (const float*)d_in[5];
  const float* b2c = (const float*)d_in[6];
  const float* g2 = (const float*)d_in[7];
  const float* be2 = (const float*)d_in[8];
  const float* cb = (const float*)d_in[9];
  float* out = (float*)d_out;
  float* ws = (float*)d_ws;

  float* h1 = ws + WS_H1;
  float* t2 = ws + WS_T2;
  unsigned short* xh = (unsigned short*)(ws + WS_XH);
  unsigned short* xl = (unsigned short*)(ws + WS_XL);
  unsigned short* wth = (unsigned short*)(ws + WS_WTH);
  unsigned short* wtl = (unsigned short*)(ws + WS_WTL);
  float* a1 = ws + WS_A1;
  float* bb1 = ws + WS_B1;
  float* a2 = ws + WS_A2;
  float* bb2 = ws + WS_B2;
  float* e2 = ws + WS_E2;
  unsigned long long* slots = (unsigned long long*)(ws + WS_SLOTS);
  float* loss = ws + WS_LOSS;

  hipMemsetAsync(slots, 0xFF, (size_t)NBATCH * LP * sizeof(unsigned long long),
                 stream);
  hipMemsetAsync(loss, 0, sizeof(float), stream);

  split_w1_kernel<<<4096, 256, 0, stream>>>(w1, wth, wtl);
  split_x_kernel<<<dim3(8, 16, NBATCH), 256, 0, stream>>>(x, xh, xl);
  conv1_mfma_kernel<<<dim3(4, 8, NBATCH), 256, 0, stream>>>(wth, wtl, xh, xl,
                                                            b1c, h1);
  bn_stats_kernel<<<DD, 256, 0, stream>>>(h1, g1, be1, a1, bb1);
  conv2_kernel<<<dim3(4, 8, NBATCH), 256, 0, stream>>>(h1, w2, b2c, a1, bb1, t2);
  bn_stats_kernel<<<DD, 256, 0, stream>>>(t2, g2, be2, a2, bb2);
  e2_kernel<<<KCB, 256, 0, stream>>>(cb, e2);
  dist_kernel<<<dim3(4, 16, NBATCH), 256, 0, stream>>>(t2, cb, a2, bb2, e2, slots);
  gather_kernel<<<dim3(8, NBATCH), 256, 0, stream>>>(t2, cb, a2, bb2, slots, out, loss);
  finalize_kernel<<<1, 64, 0, stream>>>(loss, out);
}

// Round 4
// 1202.808 us; speedup vs baseline: 5.1524x; 1.9924x over previous
//
#include <hip/hip_runtime.h>
#include <hip/hip_bf16.h>
#include <cstdint>

// Problem dims
#define DD 1024
#define LIN 1024
#define LP 511
#define LPAD 512
#define NBATCH 32
#define KCB 2048
#define BN_EPS 1e-5f

// Output layout (floats): q_st [32,1024,511], ids [32,511], commitment, codebook_loss
#define OUT_IDS 16744448u
#define OUT_LOSS 16760800u

// Workspace layout (float offsets). Region X = [WS_UNI, WS_AUX) is
// phase-multiplexed: phase0 conv1 operands; phase2 t2 + r/z planes + small planes.
#define WS_H1 0
#define WS_UNI 16777216
// phase0 (conv1):
#define WS_XH  (WS_UNI)                    // [2][32][512][1024] ushort (+512 f pad)
#define WS_XL  (WS_UNI + 16777728)
#define WS_WTH (WS_UNI + 33555456)         // [4][1024][1024] ushort
#define WS_WTL (WS_UNI + 35652608)
// phase2 (after conv1 done):
#define WS_T2  (WS_UNI)                    // fp32 [32][1024][512]
#define WS_RH  (WS_UNI + 16777216)         // [32][512][1024] ushort
#define WS_RL  (WS_UNI + 25165824)
#define WS_ZH  WS_RH                       // reuse after conv2 done
#define WS_ZL  WS_RL
#define WS_W2H (WS_UNI + 33554432)         // [1024][1024] ushort
#define WS_W2L (WS_UNI + 34078720)
#define WS_CBH (WS_UNI + 34603008)         // [2048][1024] ushort
#define WS_CBL (WS_UNI + 35651584)
#define WS_AUX (WS_UNI + 37749760)
#define WS_A1 (WS_AUX + 0)
#define WS_B1 (WS_AUX + 1024)
#define WS_A2 (WS_AUX + 2048)
#define WS_B2 (WS_AUX + 3072)
#define WS_E2 (WS_AUX + 4096)
#define WS_SLOTS (WS_AUX + 6144)
#define WS_LOSS (WS_AUX + 6144 + 32704)

typedef __attribute__((ext_vector_type(8))) short bf16x8;
typedef __attribute__((ext_vector_type(4))) float f32x4;
typedef __attribute__((ext_vector_type(4))) unsigned short ushort4v;

__device__ __forceinline__ void async_cp16(const void* gsrc, void* ldst) {
  __builtin_amdgcn_global_load_lds(
      (const __attribute__((address_space(1))) unsigned int*)gsrc,
      (__attribute__((address_space(3))) unsigned int*)ldst, 16, 0, 0);
}

__device__ __forceinline__ void bf16split(float v, unsigned short& hi, unsigned short& lo) {
  __hip_bfloat16 h = __float2bfloat16(v);
  float hf = __bfloat162float(h);
  __hip_bfloat16 l = __float2bfloat16(v - hf);
  hi = *(unsigned short*)&h;
  lo = *(unsigned short*)&l;
}

__device__ inline float blockReduce256(float v, float* sb) {
#pragma unroll
  for (int off = 32; off > 0; off >>= 1) v += __shfl_down(v, off);
  __syncthreads();
  if ((threadIdx.x & 63) == 0) sb[threadIdx.x >> 6] = v;
  __syncthreads();
  return sb[0] + sb[1] + sb[2] + sb[3];
}

// ---------------------------------------------------------------------------
// Shared MFMA tile core: 128x128 block tile, 4 waves in 2x2, each 64x64.
// Stages 128 rows x 32 halfwords of this wave's plane per K-chunk (BK=32),
// srcw = plane base for this wave (row stride 1024 elements, K-contiguous).
__device__ __forceinline__ void mfma_tiles_k(
    const unsigned short* __restrict__ srcw, unsigned short* sm, int lane,
    int wid, int nkc, int mrow, int nrow, int ko, f32x4 (&acc)[4][4]) {
  const unsigned short* As = sm;
  const unsigned short* Als = sm + 4096;
  const unsigned short* Bs = sm + 8192;
  const unsigned short* Bls = sm + 12288;
  for (int kc = 0; kc < nkc; ++kc) {
    const unsigned short* lanesrc =
        srcw + (size_t)kc * 32 + (size_t)(lane >> 2) * 1024 + (lane & 3) * 8;
    char* ldsbase = (char*)sm + wid * 8192;
#pragma unroll
    for (int q = 0; q < 8; ++q)
      async_cp16(lanesrc + (size_t)q * 16 * 1024, ldsbase + q * 1024);
    __syncthreads();
    bf16x8 fbh[4], fbl[4];
#pragma unroll
    for (int nt = 0; nt < 4; ++nt) {
      int r = nrow + nt * 16;
      fbh[nt] = *(const bf16x8*)(Bs + r * 32 + ko);
      fbl[nt] = *(const bf16x8*)(Bls + r * 32 + ko);
    }
#pragma unroll
    for (int mt = 0; mt < 4; ++mt) {
      int r = mrow + mt * 16;
      bf16x8 fah = *(const bf16x8*)(As + r * 32 + ko);
      bf16x8 fal = *(const bf16x8*)(Als + r * 32 + ko);
#pragma unroll
      for (int nt = 0; nt < 4; ++nt) {
        acc[mt][nt] = __builtin_amdgcn_mfma_f32_16x16x32_bf16(fah, fbh[nt], acc[mt][nt], 0, 0, 0);
        acc[mt][nt] = __builtin_amdgcn_mfma_f32_16x16x32_bf16(fah, fbl[nt], acc[mt][nt], 0, 0, 0);
        acc[mt][nt] = __builtin_amdgcn_mfma_f32_16x16x32_bf16(fal, fbh[nt], acc[mt][nt], 0, 0, 0);
      }
    }
    __syncthreads();
  }
}

// ---------------------------------------------------------------------------
// split w1 [o][i][t] fp32 -> wth/wtl [t][o][i] bf16 hi/lo
__global__ __launch_bounds__(256) void split_w1_kernel(
    const float* __restrict__ w, unsigned short* __restrict__ wth,
    unsigned short* __restrict__ wtl) {
  int idx = blockIdx.x * 256 + threadIdx.x;
  int o = idx >> 10, i = idx & 1023;
  float4 v = *(const float4*)&w[(size_t)idx * 4];
  float vv[4] = {v.x, v.y, v.z, v.w};
#pragma unroll
  for (int t = 0; t < 4; ++t) {
    unsigned short hi, lo;
    bf16split(vv[t], hi, lo);
    size_t off = (((size_t)(t << 10) + o) << 10) + i;
    wth[off] = hi;
    wtl[off] = lo;
  }
}

// ---------------------------------------------------------------------------
// generic row-major split: src [rows][1024] fp32 -> dsth/dstl bf16 hi/lo
__global__ __launch_bounds__(256) void split_rows_kernel(
    const float* __restrict__ src, unsigned short* __restrict__ dsth,
    unsigned short* __restrict__ dstl) {
  size_t base = ((size_t)blockIdx.x * 256 + threadIdx.x) * 4;
  float4 v = *(const float4*)&src[base];
  float vv[4] = {v.x, v.y, v.z, v.w};
  ushort4v h, l;
#pragma unroll
  for (int j = 0; j < 4; ++j) {
    unsigned short hi, lo;
    bf16split(vv[j], hi, lo);
    h[j] = hi;
    l[j] = lo;
  }
  *(ushort4v*)&dsth[base] = h;
  *(ushort4v*)&dstl[base] = l;
}

// ---------------------------------------------------------------------------
// split/transpose x [n][i][l] fp32 -> xh/xl [P][n][l>>1][i] bf16 (P = l&1)
__global__ __launch_bounds__(256) void split_x_kernel(
    const float* __restrict__ x, unsigned short* __restrict__ xh,
    unsigned short* __restrict__ xl) {
  __shared__ float lsT[128 * 65];
  const int l0 = blockIdx.x * 128;
  const int i0 = blockIdx.y * 64;
  const int nB = blockIdx.z;
  const int tid = threadIdx.x;
#pragma unroll
  for (int p = 0; p < 8; ++p) {
    int flat = p * 256 + tid;
    int row = flat >> 5, col4 = (flat & 31) * 4;
    float4 v = *(const float4*)&x[((size_t)nB * DD + i0 + row) * LIN + l0 + col4];
    lsT[(col4 + 0) * 65 + row] = v.x;
    lsT[(col4 + 1) * 65 + row] = v.y;
    lsT[(col4 + 2) * 65 + row] = v.z;
    lsT[(col4 + 3) * 65 + row] = v.w;
  }
  __syncthreads();
  const int lo2 = (l0 >> 1);
#pragma unroll
  for (int p = 0; p < 16; ++p) {
    int cp = p * 4 + (tid >> 6);
    int il = tid & 63;
    float vE = lsT[(2 * cp) * 65 + il];
    float vO = lsT[(2 * cp + 1) * 65 + il];
    unsigned short hE, lE, hO, lO;
    bf16split(vE, hE, lE);
    bf16split(vO, hO, lO);
    size_t dE = (((size_t)(0 * 32 + nB) * 512) + lo2 + cp) * 1024 + i0 + il;
    size_t dO = (((size_t)(1 * 32 + nB) * 512) + lo2 + cp) * 1024 + i0 + il;
    xh[dE] = hE; xl[dE] = lE;
    xh[dO] = hO; xl[dO] = lO;
  }
}

// ---------------------------------------------------------------------------
// transpose + per-channel affine (+optional relu) + bf16 split:
// src [n][c][LPAD] fp32 -> dsth/dstl [n][LPAD][1024] bf16 hi/lo of (a*v+b)
__global__ __launch_bounds__(256) void trans_affine_split_kernel(
    const float* __restrict__ src, const float* __restrict__ a,
    const float* __restrict__ b, unsigned short* __restrict__ dsth,
    unsigned short* __restrict__ dstl, int do_relu) {
  __shared__ float lsT[128 * 65];
  const int l0 = blockIdx.x * 128;
  const int i0 = blockIdx.y * 64;
  const int nB = blockIdx.z;
  const int tid = threadIdx.x;
#pragma unroll
  for (int p = 0; p < 8; ++p) {
    int flat = p * 256 + tid;
    int row = flat >> 5, col4 = (flat & 31) * 4;
    float4 v = *(const float4*)&src[((size_t)nB * DD + i0 + row) * LPAD + l0 + col4];
    lsT[(col4 + 0) * 65 + row] = v.x;
    lsT[(col4 + 1) * 65 + row] = v.y;
    lsT[(col4 + 2) * 65 + row] = v.z;
    lsT[(col4 + 3) * 65 + row] = v.w;
  }
  __syncthreads();
  const int il = tid & 63;
  const float ac = a[i0 + il], bc = b[i0 + il];
#pragma unroll
  for (int p = 0; p < 32; ++p) {
    int cp = p * 4 + (tid >> 6);
    float v = fmaf(ac, lsT[cp * 65 + il], bc);
    if (do_relu) v = fmaxf(v, 0.f);
    unsigned short hi, lo;
    bf16split(v, hi, lo);
    size_t d = (((size_t)nB * 512) + l0 + cp) * 1024 + i0 + il;
    dsth[d] = hi;
    dstl[d] = lo;
  }
}

// ---------------------------------------------------------------------------
// conv1 as MFMA GEMM (3-term bf16 split), h1[n][o][l'] += bias
__global__ __launch_bounds__(256) void conv1_mfma_kernel(
    const unsigned short* __restrict__ wth, const unsigned short* __restrict__ wtl,
    const unsigned short* __restrict__ xh, const unsigned short* __restrict__ xl,
    const float* __restrict__ bias, float* __restrict__ h1) {
  __shared__ unsigned short sm[16384];
  const int tid = threadIdx.x;
  const int wid = tid >> 6, lane = tid & 63;
  const int lb = blockIdx.x * 128, ob = blockIdx.y * 128, nB = blockIdx.z;

  f32x4 acc[4][4];
#pragma unroll
  for (int a = 0; a < 4; ++a)
#pragma unroll
    for (int b = 0; b < 4; ++b) acc[a][b] = (f32x4){0.f, 0.f, 0.f, 0.f};

  const int wm = wid & 1, wn = wid >> 1;
  const int mrow = (wm << 6) + (lane & 15);
  const int nrow = (wn << 6) + (lane & 15);
  const int ko = (lane >> 4) << 3;

  for (int t = 0; t < 4; ++t) {
    const unsigned short* srcw;
    if (wid == 0)
      srcw = wth + (((size_t)(t << 10) + ob) << 10);
    else if (wid == 1)
      srcw = wtl + (((size_t)(t << 10) + ob) << 10);
    else {
      const unsigned short* xp = (wid == 2) ? xh : xl;
      srcw = xp + ((((size_t)((t & 1) * 32 + nB) * 512) + lb + (t >> 1)) << 10);
    }
    mfma_tiles_k(srcw, sm, lane, wid, 32, mrow, nrow, ko, acc);
  }

#pragma unroll
  for (int mt = 0; mt < 4; ++mt) {
    const int o_base = ob + (wm << 6) + mt * 16 + ((lane >> 4) << 2);
#pragma unroll
    for (int nt = 0; nt < 4; ++nt) {
      const int l = lb + (wn << 6) + nt * 16 + (lane & 15);
      if (l < LP) {
#pragma unroll
        for (int rg = 0; rg < 4; ++rg)
          h1[((size_t)(nB << 10) + o_base + rg) * LPAD + l] =
              acc[mt][nt][rg] + bias[o_base + rg];
      }
    }
  }
}

// ---------------------------------------------------------------------------
// conv2 as MFMA GEMM: t2 = h1 + W2 @ r + b2c   (r = pre-split relu(a1*h1+b1))
__global__ __launch_bounds__(256) void conv2_mfma_kernel(
    const unsigned short* __restrict__ w2h, const unsigned short* __restrict__ w2l,
    const unsigned short* __restrict__ rh, const unsigned short* __restrict__ rl,
    const float* __restrict__ b2c, const float* __restrict__ h1,
    float* __restrict__ t2) {
  __shared__ unsigned short sm[16384];
  const int tid = threadIdx.x;
  const int wid = tid >> 6, lane = tid & 63;
  const int lb = blockIdx.x * 128, ob = blockIdx.y * 128, nB = blockIdx.z;

  f32x4 acc[4][4];
#pragma unroll
  for (int a = 0; a < 4; ++a)
#pragma unroll
    for (int b = 0; b < 4; ++b) acc[a][b] = (f32x4){0.f, 0.f, 0.f, 0.f};

  const int wm = wid & 1, wn = wid >> 1;
  const int mrow = (wm << 6) + (lane & 15);
  const int nrow = (wn << 6) + (lane & 15);
  const int ko = (lane >> 4) << 3;

  const unsigned short* srcw =
      (wid == 0) ? w2h + ((size_t)ob << 10)
    : (wid == 1) ? w2l + ((size_t)ob << 10)
    : (wid == 2) ? rh + (((size_t)nB * 512 + lb) << 10)
                 : rl + (((size_t)nB * 512 + lb) << 10);
  mfma_tiles_k(srcw, sm, lane, wid, 32, mrow, nrow, ko, acc);

#pragma unroll
  for (int mt = 0; mt < 4; ++mt) {
    const int o_base = ob + (wm << 6) + mt * 16 + ((lane >> 4) << 2);
#pragma unroll
    for (int nt = 0; nt < 4; ++nt) {
      const int l = lb + (wn << 6) + nt * 16 + (lane & 15);
      if (l < LP) {
#pragma unroll
        for (int rg = 0; rg < 4; ++rg) {
          size_t off = ((size_t)(nB << 10) + o_base + rg) * LPAD + l;
          t2[off] = h1[off] + acc[mt][nt][rg] + b2c[o_base + rg];
        }
      }
    }
  }
}

// ---------------------------------------------------------------------------
// dist as MFMA GEMM: S = cb @ z; argmin_k (e2[k] - 2S) via packed u64 atomicMin
__global__ __launch_bounds__(256) void dist_mfma_kernel(
    const unsigned short* __restrict__ cbh, const unsigned short* __restrict__ cbl,
    const unsigned short* __restrict__ zh, const unsigned short* __restrict__ zl,
    const float* __restrict__ e2, unsigned long long* __restrict__ slots) {
  __shared__ unsigned short sm[16384];
  __shared__ unsigned long long best[128];
  const int tid = threadIdx.x;
  const int wid = tid >> 6, lane = tid & 63;
  const int lb = blockIdx.x * 128, kb = blockIdx.y * 128, nB = blockIdx.z;

  f32x4 acc[4][4];
#pragma unroll
  for (int a = 0; a < 4; ++a)
#pragma unroll
    for (int b = 0; b < 4; ++b) acc[a][b] = (f32x4){0.f, 0.f, 0.f, 0.f};

  const int wm = wid & 1, wn = wid >> 1;
  const int mrow = (wm << 6) + (lane & 15);
  const int nrow = (wn << 6) + (lane & 15);
  const int ko = (lane >> 4) << 3;

  const unsigned short* srcw =
      (wid == 0) ? cbh + ((size_t)kb << 10)
    : (wid == 1) ? cbl + ((size_t)kb << 10)
    : (wid == 2) ? zh + (((size_t)nB * 512 + lb) << 10)
                 : zl + (((size_t)nB * 512 + lb) << 10);
  mfma_tiles_k(srcw, sm, lane, wid, 32, mrow, nrow, ko, acc);

  if (tid < 128) best[tid] = ~0ULL;
  __syncthreads();
#pragma unroll
  for (int nt = 0; nt < 4; ++nt) {
    const int col = (wn << 6) + nt * 16 + (lane & 15);
    float dmin = 3.4e38f;
    int kmin = 0;
#pragma unroll
    for (int mt = 0; mt < 4; ++mt) {
      const int kbase = kb + (wm << 6) + mt * 16 + ((lane >> 4) << 2);
#pragma unroll
      for (int rg = 0; rg < 4; ++rg) {
        float dist = fmaf(-2.f, acc[mt][nt][rg], e2[kbase + rg]);
        if (dist < dmin) { dmin = dist; kmin = kbase + rg; }
      }
    }
    unsigned long long pk =
        ((unsigned long long)__float_as_uint(dmin) << 32) | (unsigned)kmin;
    atomicMin(&best[col], pk);
  }
  __syncthreads();
  if (tid < 128) {
    int l = lb + tid;
    if (l < LP) atomicMin(&slots[(size_t)nB * LP + l], best[tid]);
  }
}

// ---------------------------------------------------------------------------
__global__ __launch_bounds__(256) void bn_stats_kernel(
    const float* __restrict__ src, const float* __restrict__ gamma,
    const float* __restrict__ beta, float* __restrict__ a_out,
    float* __restrict__ b_out) {
  __shared__ float sb[4];
  const int c = blockIdx.x;
  const float* p = src + (size_t)c * LPAD;
  float s1 = 0.f, s2 = 0.f;
  for (int idx = threadIdx.x; idx < NBATCH * LP; idx += 256) {
    int nn = idx / LP;
    int l = idx - nn * LP;
    float v = p[(size_t)nn * DD * LPAD + l];
    s1 += v;
    s2 = fmaf(v, v, s2);
  }
  s1 = blockReduce256(s1, sb);
  s2 = blockReduce256(s2, sb);
  if (threadIdx.x == 0) {
    const float inv = 1.f / (float)(NBATCH * LP);
    float m = s1 * inv;
    float var = fmaf(-m, m, s2 * inv);
    float a = gamma[c] * rsqrtf(var + BN_EPS);
    a_out[c] = a;
    b_out[c] = fmaf(-m, a, beta[c]);
  }
}

// ---------------------------------------------------------------------------
__global__ __launch_bounds__(256) void e2_kernel(const float* __restrict__ cb,
                                                 float* __restrict__ e2) {
  __shared__ float sb[4];
  const int k = blockIdx.x;
  float s = 0.f;
  for (int d = threadIdx.x; d < DD; d += 256) {
    float v = cb[(size_t)k * DD + d];
    s = fmaf(v, v, s);
  }
  s = blockReduce256(s, sb);
  if (threadIdx.x == 0) e2[k] = s;
}

// ---------------------------------------------------------------------------
__global__ __launch_bounds__(256) void gather_kernel(
    const float* __restrict__ t2, const float* __restrict__ cb,
    const float* __restrict__ a2, const float* __restrict__ b2,
    const unsigned long long* __restrict__ slots, float* __restrict__ out,
    float* __restrict__ loss_acc) {
  __shared__ int ks[64];
  __shared__ float sb[4];
  const int l0 = blockIdx.x * 64;
  const int n = blockIdx.y;
  const int tid = threadIdx.x, tx = tid & 63, ty = tid >> 6;
  if (tid < 64) {
    int l = l0 + tid;
    int k = 0;
    if (l < LP) {
      k = (int)(unsigned)(slots[(size_t)n * LP + l] & 0xffffffffULL);
      out[OUT_IDS + (size_t)n * LP + l] = (float)k;
    }
    ks[tid] = k;
  }
  __syncthreads();
  const int l = l0 + tx;
  const bool valid = (l < LP);
  const int k = ks[tx];
  const float* cbk = cb + (size_t)k * DD;
  const float* tn = t2 + (size_t)n * DD * LPAD;
  float* qo = out + (size_t)n * DD * LP;
  float lsum = 0.f;
  for (int d0 = 0; d0 < DD; d0 += 4) {
    const int d = d0 + ty;
    float q = cbk[d];
    if (valid) {
      float z = fmaf(a2[d], tn[(size_t)d * LPAD + l], b2[d]);
      qo[(size_t)d * LP + l] = q;
      float e = z - q;
      lsum = fmaf(e, e, lsum);
    }
  }
  lsum = blockReduce256(lsum, sb);
  if (tid == 0) atomicAdd(loss_acc, lsum);
}

__global__ void finalize_kernel(const float* __restrict__ loss_acc,
                                float* __restrict__ out) {
  if (threadIdx.x == 0) {
    float m = loss_acc[0] * (1.f / 16744448.f);
    out[OUT_LOSS] = m;
    out[OUT_LOSS + 1] = m;
  }
}

// ---------------------------------------------------------------------------
extern "C" void kernel_launch(void* const* d_in, const int* in_sizes, int n_in,
                              void* d_out, int out_size, void* d_ws,
                              size_t ws_size, hipStream_t stream) {
  const float* x = (const float*)d_in[0];
  const float* w1 = (const float*)d_in[1];
  const float* b1c = (const float*)d_in[2];
  const float* g1 = (const float*)d_in[3];
  const float* be1 = (const float*)d_in[4];
  const float* w2 = (const float*)d_in[5];
  const float* b2c = (const float*)d_in[6];
  const float* g2 = (const float*)d_in[7];
  const float* be2 = (const float*)d_in[8];
  const float* cb = (const float*)d_in[9];
  float* out = (float*)d_out;
  float* ws = (float*)d_ws;

  float* h1 = ws + WS_H1;
  float* t2 = ws + WS_T2;
  unsigned short* xh = (unsigned short*)(ws + WS_XH);
  unsigned short* xl = (unsigned short*)(ws + WS_XL);
  unsigned short* wth = (unsigned short*)(ws + WS_WTH);
  unsigned short* wtl = (unsigned short*)(ws + WS_WTL);
  unsigned short* rh = (unsigned short*)(ws + WS_RH);
  unsigned short* rl = (unsigned short*)(ws + WS_RL);
  unsigned short* zh = (unsigned short*)(ws + WS_ZH);
  unsigned short* zl = (unsigned short*)(ws + WS_ZL);
  unsigned short* w2h = (unsigned short*)(ws + WS_W2H);
  unsigned short* w2l = (unsigned short*)(ws + WS_W2L);
  unsigned short* cbh = (unsigned short*)(ws + WS_CBH);
  unsigned short* cbl = (unsigned short*)(ws + WS_CBL);
  float* a1 = ws + WS_A1;
  float* bb1 = ws + WS_B1;
  float* a2 = ws + WS_A2;
  float* bb2 = ws + WS_B2;
  float* e2 = ws + WS_E2;
  unsigned long long* slots = (unsigned long long*)(ws + WS_SLOTS);
  float* loss = ws + WS_LOSS;

  (void)hipMemsetAsync(slots, 0xFF,
                       (size_t)NBATCH * LP * sizeof(unsigned long long), stream);
  (void)hipMemsetAsync(loss, 0, sizeof(float), stream);

  // phase 0: conv1 operand prep + conv1
  split_w1_kernel<<<4096, 256, 0, stream>>>(w1, wth, wtl);
  split_x_kernel<<<dim3(8, 16, NBATCH), 256, 0, stream>>>(x, xh, xl);
  conv1_mfma_kernel<<<dim3(4, 8, NBATCH), 256, 0, stream>>>(wth, wtl, xh, xl,
                                                            b1c, h1);
  // phase 1: BN1 stats, then conv2 operand prep (overlays dead conv1 planes)
  bn_stats_kernel<<<DD, 256, 0, stream>>>(h1, g1, be1, a1, bb1);
  split_rows_kernel<<<1024, 256, 0, stream>>>(w2, w2h, w2l);
  split_rows_kernel<<<2048, 256, 0, stream>>>(cb, cbh, cbl);
  e2_kernel<<<KCB, 256, 0, stream>>>(cb, e2);
  trans_affine_split_kernel<<<dim3(4, 16, NBATCH), 256, 0, stream>>>(
      h1, a1, bb1, rh, rl, 1);
  conv2_mfma_kernel<<<dim3(4, 8, NBATCH), 256, 0, stream>>>(w2h, w2l, rh, rl,
                                                            b2c, h1, t2);
  // phase 2: BN2 stats, z prep (overlays dead r planes), dist, gather
  bn_stats_kernel<<<DD, 256, 0, stream>>>(t2, g2, be2, a2, bb2);
  trans_affine_split_kernel<<<dim3(4, 16, NBATCH), 256, 0, stream>>>(
      t2, a2, bb2, zh, zl, 0);
  dist_mfma_kernel<<<dim3(4, 16, NBATCH), 256, 0, stream>>>(cbh, cbl, zh, zl,
                                                            e2, slots);
  gather_kernel<<<dim3(8, NBATCH), 256, 0, stream>>>(t2, cb, a2, bb2, slots, out, loss);
  finalize_kernel<<<1, 64, 0, stream>>>(loss, out);
}